// Round 13
// baseline (338.718 us; speedup 1.0000x reference)
//
#include <hip/hip_runtime.h>
#include <hip/hip_bf16.h>

typedef unsigned int u32;
typedef unsigned short u16;
typedef __attribute__((ext_vector_type(8))) short short8;   // 8 bf16 (4 VGPRs)
typedef __attribute__((ext_vector_type(4))) float f32x4;    // 4 fp32 acc

#define MFMA(a,b,c) __builtin_amdgcn_mfma_f32_16x16x32_bf16(a,b,c,0,0,0)

// ---------------- helpers ----------------
__device__ __forceinline__ float bf2f(u16 u){ return __uint_as_float(((u32)u)<<16); }
__device__ __forceinline__ float lo16(u32 w){ return __uint_as_float(w<<16); }
__device__ __forceinline__ float hi16(u32 w){ return __uint_as_float(w & 0xffff0000u); }
__device__ __forceinline__ u16 f2b(float x){ __hip_bfloat16 h=__float2bfloat16(x); return *(u16*)&h; }
__device__ __forceinline__ u32 pack2(float a, float b){ return (u32)f2b(a) | ((u32)f2b(b)<<16); }

// canonical f32 weight pool: element offsets (verified R5)
#define O_Wf1 0
#define O_bf1 1024
#define O_Wf2 1280
#define O_bf2 66816
#define O_Wu1 67072
#define O_bu1 68096
#define O_Wu2 68352
#define O_bu2 133888
#define O_remb 134144
#define O_Wq 134656
#define O_bq 200192
#define O_Wk 200448
#define O_bk 265984
#define O_Wv 266240
#define O_bv 331776
#define O_Wo 332032
#define O_bo 397568
#define O_ag 397824
#define O_ab 398080
#define O_lg 398336
#define O_lb 399616
#define O_Wc1 400896
#define O_bc1 728576
#define O_Wc2 728832
#define O_bc2 729088
#define TOTW 729089

static __device__ const int c_off[26] = {
  0,1024,1280,66816,67072,68096,68352,133888,134144,134656,200192,200448,
  265984,266240,331776,332032,397568,397824,398080,398336,399616,400896,
  728576,728832,729088,729089};

struct WPar { const void* src[25]; const u32* traj; float* dst; };

__device__ __forceinline__ int detect_bf16(const u32* traj){
  int inr = 0;
#pragma unroll 1
  for(int i=0;i<64;i++){
    u32 e = (traj[i]>>7) & 0xffu;
    inr += (e >= 0x58u && e <= 0x9au) ? 1 : 0;
  }
  return (inr==64) ? 1 : 0;
}

// ---------------- K0: canonicalize all weights to f32 (verified R5) ----------------
__global__ __launch_bounds__(256) void k_conv(WPar p){
  __shared__ int fl;
  if(threadIdx.x==0) fl = detect_bf16(p.traj);
  __syncthreads();
  int mode = fl;
  int g = blockIdx.x*256 + threadIdx.x;
  if(g >= TOTW) return;
  int t = 0;
#pragma unroll 1
  for(int i=1;i<25;i++) if(g >= c_off[i]) t = i;
  int j = g - c_off[t];
  float v = mode ? bf2f(((const u16*)p.src[t])[j]) : ((const float*)p.src[t])[j];
  p.dst[g] = v;
}

// ---------------- K1: mean-pool + mask normalize (verified R5) ----------------
__global__ __launch_bounds__(256) void k_pool(const void* __restrict__ traj, const u32* __restrict__ mraw,
                                              float* __restrict__ pooled, int* __restrict__ maskI){
  __shared__ int fl;
  if(threadIdx.x==0) fl = detect_bf16((const u32*)traj);
  __syncthreads();
  int t = blockIdx.x*256 + threadIdx.x;
  int b = t>>8, r = t&255;
  float s = 0.f;
  if(fl){
    const u16* tp = (const u16*)traj + (size_t)b*12800 + r;
#pragma unroll 1
    for(int l=0;l<50;l++) s += bf2f(tp[l*256]);
  } else {
    const float* tp = (const float*)traj + (size_t)b*12800 + r;
#pragma unroll 1
    for(int l=0;l<50;l++) s += tp[l*256];
  }
  pooled[t] = s * 0.02f;
  if(t < 16384){
    bool isByte = false;
#pragma unroll
    for(int w=0;w<16;w++) isByte |= (mraw[w] > 1u);
    int v;
    if(isByte){ u32 w = mraw[t>>2]; v = (int)((w >> ((t&3)*8)) & 0xffu); }
    else      { v = (int)mraw[t]; }
    maskI[t] = (v!=0) ? 1 : 0;
  }
}

// ---------------- K2: transpose f32 -> bf16 WT in MFMA-fragment-major order ----------------
static __device__ const int t_src[6] = {O_Wf2, O_Wu2, O_Wq, O_Wk, O_Wv, O_Wo};
__global__ __launch_bounds__(256) void k_trans(const float* __restrict__ WF, u16* __restrict__ WT){
  __shared__ float tl[64][65];
  int mat = blockIdx.x >> 4, tile = blockIdx.x & 15;
  int kt = (tile>>2)*64, nt = (tile&3)*64;
  int t = threadIdx.x;
  int i = t>>2, c4 = (t&3)*16;
  const float* src = WF + t_src[mat] + (kt+i)*256 + nt + c4;
#pragma unroll
  for(int c=0;c<16;c+=4) *(float4*)&tl[i][c4+c] = *(const float4*)(src + c);
  __syncthreads();
  int n = nt + i;
  int tile_n = n >> 4, nl = n & 15;
  int ks = (kt + c4) >> 5;
  u16* base = WT + mat*65536;
#pragma unroll
  for(int h=0; h<2; h++){
    int quad = ((c4 + h*8) >> 3) & 3;
    short8 v;
#pragma unroll
    for(int j=0;j<8;j++) v[j] = (short)f2b(tl[c4 + h*8 + j][i]);
    *(short8*)(base + ((tile_n*8 + ks)*64 + quad*16 + nl)*8) = v;
  }
}

// ---------------- K3: WTC (lg-folded, d-combined Wc1^T, K=1024) in fragment-major order ----------------
__global__ __launch_bounds__(256) void k_transc(const float* __restrict__ WF, u16* __restrict__ WTC){
  __shared__ float tl[64][65];
  int seg = blockIdx.x >> 4, tile = blockIdx.x & 15;
  int jt = (tile>>2)*64, nt = (tile&3)*64;
  int t = threadIdx.x;
  int i = t>>2, c4 = (t&3)*16;
  int j = jt + i;
#pragma unroll 1
  for(int c=0;c<16;c++){
    int n = nt + c4 + c;
    float v;
    if(seg==0)      v = WF[O_lg+j]*WF[O_Wc1 + j*256 + n] + WF[O_lg+768+j]*WF[O_Wc1 + (768+j)*256 + n];
    else if(seg==1) v = WF[O_lg+256+j]*WF[O_Wc1+(256+j)*256+n] - WF[O_lg+768+j]*WF[O_Wc1+(768+j)*256+n];
    else if(seg==2) v = WF[O_lg+512+j]*WF[O_Wc1+(512+j)*256+n];
    else            v = WF[O_lg+1024+j]*WF[O_Wc1+(1024+j)*256+n];
    tl[i][c4+c] = v;
  }
  __syncthreads();
  int n = nt + i;
  int tile_n = n >> 4, nl = n & 15;
  int kbase = seg*256 + jt + c4;
  int ks = kbase >> 5;
#pragma unroll
  for(int h=0; h<2; h++){
    int quad = ((kbase + h*8) >> 3) & 3;
    short8 v;
#pragma unroll
    for(int jj=0;jj<8;jj++) v[jj] = (short)f2b(tl[c4 + h*8 + jj][i]);
    *(short8*)(WTC + ((tile_n*32 + ks)*64 + quad*16 + nl)*8) = v;
  }
}

// ---------------- K4: U[n] = sum lb*Wc1 + bc1 ; G[n] = sum lg*Wc1 (grid=256) ----------------
__global__ __launch_bounds__(256) void k_prep(const float* __restrict__ WF, float* __restrict__ UG){
  __shared__ float ru[4], rg[4];
  int n = blockIdx.x;
  int t = threadIdx.x;
  float u = 0.f, g = 0.f;
#pragma unroll
  for(int j=0;j<5;j++){
    int m = t + j*256;
    float w = WF[O_Wc1 + m*256 + n];
    u = fmaf(WF[O_lb+m], w, u);
    g = fmaf(WF[O_lg+m], w, g);
  }
#pragma unroll
  for(int o=32;o>0;o>>=1){ u += __shfl_xor(u,o,64); g += __shfl_xor(g,o,64); }
  int wv = t>>6;
  if((t&63)==0){ ru[wv]=u; rg[wv]=g; }
  __syncthreads();
  if(t==0){
    UG[n]     = ru[0]+ru[1]+ru[2]+ru[3] + WF[O_bc1+n];
    UG[256+n] = rg[0]+rg[1]+rg[2]+rg[3];
  }
}

// ---------------- K5: enc layer 1 -> h bf16 [16384][256] ----------------
__global__ __launch_bounds__(256) void k_h(const float* __restrict__ WF, const float* __restrict__ pooled,
                                           const int* __restrict__ roles, u32* __restrict__ hb){
  int g = blockIdx.x*256 + threadIdx.x;       // 1,048,576 total, 4 elems each
  int r = g>>6, e0 = (g&63)*4;
  float4 pl = *(const float4*)(pooled + r*4);
  int role = roles[r];
  const float* W1 = WF + (role ? O_Wu1 : O_Wf1);
  const float* b1 = WF + (role ? O_bu1 : O_bf1);
  float h[4];
#pragma unroll
  for(int c=0;c<4;c++){
    int e = e0+c;
    float v = b1[e] + pl.x*W1[e] + pl.y*W1[256+e] + pl.z*W1[512+e] + pl.w*W1[768+e];
    h[c] = fmaxf(v, 0.f);
  }
  hb[(r*256+e0)>>1]     = pack2(h[0],h[1]);
  hb[((r*256+e0)>>1)+1] = pack2(h[2],h[3]);
}

// ---------------- shared GEMM pieces (BM=32, K=256, LDS stride 264) ----------------
__device__ __forceinline__ void stageA256(const u16* __restrict__ A, long row0, u16* As){
  int t = threadIdx.x;
  int r = t >> 3, c0 = (t & 7) * 32;
  const u16* src = A + (row0 + r)*256 + c0;
  u16* dst = As + r*264 + c0;
#pragma unroll
  for(int i=0;i<4;i++) *(short8*)(dst + i*8) = *(const short8*)(src + i*8);
}

// B in fragment-major order: frag(tile,ks) at ((tile*8+ks)*64 + lane)*8 — 1KB coalesced/wave
__device__ __forceinline__ void mmK256(const u16* As, const u16* __restrict__ WT, int wv,
                                       int colL, int quad, int lane, f32x4 acc[2][4]){
#pragma unroll
  for(int ks=0; ks<8; ks++){
    short8 a0 = *(short8*)(As + colL*264 + ks*32 + quad*8);
    short8 a1 = *(short8*)(As + (colL+16)*264 + ks*32 + quad*8);
#pragma unroll
    for(int ct=0; ct<4; ct++){
      short8 b = *(const short8*)(WT + (((wv*4+ct)*8 + ks)*64 + lane)*8);
      acc[0][ct] = MFMA(a0, b, acc[0][ct]);
      acc[1][ct] = MFMA(a1, b, acc[1][ct]);
    }
  }
}

// ---------------- K6: enc layer 2 dual GEMM + select + mask + remb -> x0 bf16 ----------------
__global__ __launch_bounds__(256,2) void k_enc2(const float* __restrict__ WF, const u16* __restrict__ hb,
                                                const int* __restrict__ roles, const int* __restrict__ maskI,
                                                const u16* __restrict__ WT2F, const u16* __restrict__ WT2U,
                                                u16* __restrict__ x0b){
  __shared__ u16 As[32*264];
  __shared__ int roleS[32], maskS[32];
  long row0 = (long)blockIdx.x*32;
  int t = threadIdx.x;
  stageA256(hb, row0, As);
  if(t<32){ roleS[t]=roles[row0+t]; maskS[t]=maskI[row0+t]; }
  __syncthreads();
  int lane = t & 63, wv = t >> 6;
  int colL = lane & 15, quad = lane >> 4;
  f32x4 accF[2][4] = {};
  f32x4 accU[2][4] = {};
  mmK256(As, WT2F, wv, colL, quad, lane, accF);
  mmK256(As, WT2U, wv, colL, quad, lane, accU);
#pragma unroll
  for(int ct=0; ct<4; ct++){
    int col = wv*64 + ct*16 + colL;
    float bfc = WF[O_bf2+col], buc = WF[O_bu2+col];
    float r0c = WF[O_remb+col], r1c = WF[O_remb+256+col];
#pragma unroll
    for(int rt=0; rt<2; rt++)
#pragma unroll
    for(int reg=0; reg<4; reg++){
      int row = rt*16 + quad*4 + reg;
      float vf = accF[rt][ct][reg] + bfc;
      float vu = accU[rt][ct][reg] + buc;
      int ro = roleS[row];
      float v = ro ? vu : vf;
      v = maskS[row] ? v : 0.f;
      v += ro ? r1c : r0c;
      x0b[(size_t)(row0+row)*256 + col] = f2b(v);
    }
  }
}

// ---------------- K7: qkv GEMM (grid.y selects q/k/v) -> bf16 buffers ----------------
static __device__ const int qkv_b[3] = {O_bq, O_bk, O_bv};
__global__ __launch_bounds__(256,2) void k_qkv(const float* __restrict__ WF, const u16* __restrict__ x0b,
                                               const u16* __restrict__ WTQ, u16* __restrict__ qout){
  __shared__ u16 As[32*264];
  long row0 = (long)blockIdx.x*32;
  int y = blockIdx.y;
  stageA256(x0b, row0, As);
  __syncthreads();
  int t = threadIdx.x;
  int lane = t & 63, wv = t >> 6;
  int colL = lane & 15, quad = lane >> 4;
  f32x4 acc[2][4] = {};
  mmK256(As, WTQ + y*65536, wv, colL, quad, lane, acc);
  u16* outp = qout + (size_t)y*4194304;
  int bo = qkv_b[y];
#pragma unroll
  for(int ct=0; ct<4; ct++){
    int col = wv*64 + ct*16 + colL;
    float bc = WF[bo+col];
#pragma unroll
    for(int rt=0; rt<2; rt++)
#pragma unroll
    for(int reg=0; reg<4; reg++){
      int row = rt*16 + quad*4 + reg;
      outp[(size_t)(row0+row)*256 + col] = f2b(acc[rt][ct][reg] + bc);
    }
  }
}

// ---------------- K8: attention, spill-free split (verified R12) ----------------
__global__ __launch_bounds__(256,1) void k_attn5(const u32* __restrict__ qb, const u32* __restrict__ kb,
                                                 const u32* __restrict__ vb, const int* __restrict__ maskI,
                                                 u32* __restrict__ ctxb){
  __shared__ uint4 Ks4[64*8], Vs4[64*8];
  __shared__ float Ps[64*68];
  __shared__ int maskS[64];
  const int t = threadIdx.x;
  const int b = blockIdx.x, h = blockIdx.y;
  {
    int r = t>>2, c2 = (t&3)*2;
    size_t g = (size_t)(b*64+r)*128 + h*32;
    const uint4* kr = (const uint4*)(kb + g);
    const uint4* vr = (const uint4*)(vb + g);
    int rot = r + (r>>4);
#pragma unroll
    for(int i=0;i<2;i++){
      int c = c2 + i;
      int pc = (c + rot) & 7;
      Ks4[r*8 + pc] = kr[c];
      Vs4[r*8 + pc] = vr[c];
    }
    if(t<64) maskS[t] = maskI[b*64+t];
  }
  const int lane = t & 63;
  const int wv = __builtin_amdgcn_readfirstlane(t>>6);
  const int qq = lane>>2, part = lane&3;
  const int q = wv*16 + qq;
  uint4 qp[8];                                  // packed Q: 32 VGPRs
  {
    const uint4* qr = (const uint4*)(qb + (size_t)(b*64+q)*128 + h*32);
#pragma unroll
    for(int c=0;c<8;c++) qp[c] = qr[c];
  }
  __syncthreads();
  float s[16];
#pragma unroll 1
  for(int jj=0;jj<16;jj++){
    int j = part*16 + jj;
    int rot = j + (j>>4);
    const uint4* kr = Ks4 + j*8;
    float d0=0.f, d1=0.f;
#pragma unroll
    for(int c=0;c<8;c++){
      uint4 w = kr[(c + rot) & 7];
      uint4 qw = qp[c];
      d0 = fmaf(lo16(qw.x), lo16(w.x), d0);
      d1 = fmaf(hi16(qw.x), hi16(w.x), d1);
      d0 = fmaf(lo16(qw.y), lo16(w.y), d0);
      d1 = fmaf(hi16(qw.y), hi16(w.y), d1);
      d0 = fmaf(lo16(qw.z), lo16(w.z), d0);
      d1 = fmaf(hi16(qw.z), hi16(w.z), d1);
      d0 = fmaf(lo16(qw.w), lo16(w.w), d0);
      d1 = fmaf(hi16(qw.w), hi16(w.w), d1);
    }
    s[jj] = maskS[j] ? (d0+d1)*0.125f : -1e9f;
  }
  float mx = s[0];
#pragma unroll
  for(int jj=1;jj<16;jj++) mx = fmaxf(mx, s[jj]);
  mx = fmaxf(mx, __shfl_xor(mx,1,64));
  mx = fmaxf(mx, __shfl_xor(mx,2,64));
  float sum = 0.f;
#pragma unroll
  for(int jj=0;jj<16;jj++){ s[jj] = __expf(s[jj]-mx); sum += s[jj]; }
  sum += __shfl_xor(sum,1,64);
  sum += __shfl_xor(sum,2,64);
  float inv = 1.f/sum;
#pragma unroll
  for(int jj=0;jj<16;jj++) Ps[q*68 + part*16 + jj] = s[jj]*inv;
  __syncthreads();
  float cx[16];
#pragma unroll
  for(int c=0;c<16;c++) cx[c]=0.f;
#pragma unroll 2
  for(int j=0;j<64;j++){
    float p = Ps[q*68 + j];
    int rot = j + (j>>4);
    const uint4* vr = Vs4 + j*8;
    uint4 w0 = vr[(part*2 + rot) & 7];
    uint4 w1 = vr[(part*2 + 1 + rot) & 7];
    cx[0] = fmaf(p, lo16(w0.x), cx[0]);  cx[1] = fmaf(p, hi16(w0.x), cx[1]);
    cx[2] = fmaf(p, lo16(w0.y), cx[2]);  cx[3] = fmaf(p, hi16(w0.y), cx[3]);
    cx[4] = fmaf(p, lo16(w0.z), cx[4]);  cx[5] = fmaf(p, hi16(w0.z), cx[5]);
    cx[6] = fmaf(p, lo16(w0.w), cx[6]);  cx[7] = fmaf(p, hi16(w0.w), cx[7]);
    cx[8] = fmaf(p, lo16(w1.x), cx[8]);  cx[9] = fmaf(p, hi16(w1.x), cx[9]);
    cx[10]= fmaf(p, lo16(w1.y), cx[10]); cx[11]= fmaf(p, hi16(w1.y), cx[11]);
    cx[12]= fmaf(p, lo16(w1.z), cx[12]); cx[13]= fmaf(p, hi16(w1.z), cx[13]);
    cx[14]= fmaf(p, lo16(w1.w), cx[14]); cx[15]= fmaf(p, hi16(w1.w), cx[15]);
  }
  u32 ow[8];
#pragma unroll
  for(int i=0;i<8;i++) ow[i] = pack2(cx[2*i], cx[2*i+1]);
  u32* orow = ctxb + (size_t)(b*64+q)*128 + h*32 + part*8;
  *(uint4*)(orow)     = make_uint4(ow[0],ow[1],ow[2],ow[3]);
  *(uint4*)(orow + 4) = make_uint4(ow[4],ow[5],ow[6],ow[7]);
}

// ---------------- K9: oproj GEMM + residual + LN -> x1 f32 ----------------
__global__ __launch_bounds__(256,2) void k_oproj(const float* __restrict__ WF, const u16* __restrict__ ctxb,
                                                 const u16* __restrict__ x0b, const u16* __restrict__ WTO,
                                                 float* __restrict__ x1){
  __shared__ u16 As[32*264];
  __shared__ float Sred[4][32], Qred[4][32], Mrow[32], Rrow[32];
  long row0 = (long)blockIdx.x*32;
  stageA256(ctxb, row0, As);
  __syncthreads();
  int t = threadIdx.x;
  int lane = t & 63, wv = t >> 6;
  int colL = lane & 15, quad = lane >> 4;
  f32x4 acc[2][4] = {};
  mmK256(As, WTO, wv, colL, quad, lane, acc);
  float S[2][4] = {}, Q[2][4] = {};
#pragma unroll
  for(int ct=0; ct<4; ct++){
    int col = wv*64 + ct*16 + colL;
    float bc = WF[O_bo+col];
#pragma unroll
    for(int rt=0; rt<2; rt++)
#pragma unroll
    for(int reg=0; reg<4; reg++){
      int row = rt*16 + quad*4 + reg;
      float y = acc[rt][ct][reg] + bc + bf2f(x0b[(size_t)(row0+row)*256 + col]);
      acc[rt][ct][reg] = y;
      S[rt][reg] += y; Q[rt][reg] += y*y;
    }
  }
#pragma unroll
  for(int o=1;o<16;o<<=1)
#pragma unroll
  for(int rt=0;rt<2;rt++)
#pragma unroll
  for(int reg=0;reg<4;reg++){ S[rt][reg] += __shfl_xor(S[rt][reg],o); Q[rt][reg] += __shfl_xor(Q[rt][reg],o); }
  if(colL==0){
#pragma unroll
    for(int rt=0;rt<2;rt++)
#pragma unroll
    for(int reg=0;reg<4;reg++){
      Sred[wv][rt*16+quad*4+reg] = S[rt][reg];
      Qred[wv][rt*16+quad*4+reg] = Q[rt][reg];
    }
  }
  __syncthreads();
  if(t<32){
    float s = Sred[0][t]+Sred[1][t]+Sred[2][t]+Sred[3][t];
    float q = Qred[0][t]+Qred[1][t]+Qred[2][t]+Qred[3][t];
    float mean = s*(1.f/256.f);
    float var  = q*(1.f/256.f) - mean*mean;
    Mrow[t] = mean; Rrow[t] = rsqrtf(var + 1e-5f);
  }
  __syncthreads();
#pragma unroll
  for(int ct=0; ct<4; ct++){
    int col = wv*64 + ct*16 + colL;
    float gc = WF[O_ag+col], bc = WF[O_ab+col];
#pragma unroll
    for(int rt=0; rt<2; rt++)
#pragma unroll
    for(int reg=0; reg<4; reg++){
      int row = rt*16 + quad*4 + reg;
      x1[(size_t)(row0+row)*256 + col] = (acc[rt][ct][reg]-Mrow[row])*Rrow[row]*gc + bc;
    }
  }
}

// ---------------- K11: classifier GEMM, 2-pass K-split + FUSED per-pair LN stats ----------------
// Pass 0 stages ef|eu and computes the 1280-feature S/Q inline (8 lanes/row,
// shfl_xor reduce) -> rs/mrs in LDS. k_stats kernel deleted.
__global__ __launch_bounds__(256) void k_cls(const float* __restrict__ WF, const float* __restrict__ x1,
                                             const int* __restrict__ pairs, const u16* __restrict__ WTC,
                                             const float* __restrict__ UG, float* __restrict__ out){
  __shared__ u16 As[32*512];                   // 32 KB; XOR-swizzled chunks of 8
  __shared__ float rsS[32], mrsS[32];
  int t = threadIdx.x;
  int lane = t & 63, wv = t >> 6;
  int colL = lane & 15, quad = lane >> 4;
  int rxl = colL & 7;
  int r = t>>3, t8 = t&7, rx = r&7;
  long pr = (long)blockIdx.x*32 + r;
  int bb = (int)(pr>>7);
  int i0 = pairs[pr*2], i1 = pairs[pr*2+1];
  const float* ef = x1 + (size_t)(bb*64+i0)*256 + t8*32;
  const float* eu = x1 + (size_t)(bb*64+i1)*256 + t8*32;
  f32x4 acc[2][4] = {};
#pragma unroll 1
  for(int pass=0; pass<2; pass++){
    float S=0.f, Q=0.f;
#pragma unroll
    for(int c=0;c<4;c++){
      float e[8], u[8];
      *(float4*)(e)   = *(const float4*)(ef + c*8);
      *(float4*)(e+4) = *(const float4*)(ef + c*8 + 4);
      *(float4*)(u)   = *(const float4*)(eu + c*8);
      *(float4*)(u+4) = *(const float4*)(eu + c*8 + 4);
      short8 f0, f1;
#pragma unroll
      for(int j=0;j<8;j++){
        float d = e[j]-u[j];
        if(pass==0){
          float p = e[j]*u[j];
          S += 2.f*e[j] + fabsf(d) + p;                 // ef+eu+|d|+d+p, d terms cancel to 2ef
          Q += e[j]*e[j] + u[j]*u[j] + 2.f*d*d + p*p;
          f0[j] = (short)f2b(e[j]);        f1[j] = (short)f2b(u[j]);
        } else {
          f0[j] = (short)f2b(fabsf(d));    f1[j] = (short)f2b(e[j]*u[j]);
        }
      }
      int cc = t8*4 + c;
      *(short8*)(As + r*512 + (( 0 + cc)^rx)*8) = f0;
      *(short8*)(As + r*512 + ((32 + cc)^rx)*8) = f1;
    }
    if(pass==0){
#pragma unroll
      for(int o=1;o<8;o<<=1){ S += __shfl_xor(S,o); Q += __shfl_xor(Q,o); }
      if(t8==0){
        float mean = S*(1.f/1280.f);
        float var  = Q*(1.f/1280.f) - mean*mean;
        float rs = rsqrtf(var + 1e-5f);
        rsS[r] = rs; mrsS[r] = mean*rs;
      }
    }
    __syncthreads();
#pragma unroll 2
    for(int ks=0; ks<16; ks++){
      short8 a0 = *(short8*)(As + colL*512      + ((ks*4+quad)^rxl)*8);
      short8 a1 = *(short8*)(As + (colL+16)*512 + ((ks*4+quad)^rxl)*8);
      int kst = pass*16 + ks;
#pragma unroll
      for(int ct=0;ct<4;ct++){
        short8 b = *(const short8*)(WTC + (size_t)(((wv*4+ct)*32 + kst)*64 + lane)*8);
        acc[0][ct] = MFMA(a0, b, acc[0][ct]);
        acc[1][ct] = MFMA(a1, b, acc[1][ct]);
      }
    }
    __syncthreads();
  }
  float rsv[2][4], mrsv[2][4];
#pragma unroll
  for(int rt=0;rt<2;rt++)
#pragma unroll
  for(int reg=0;reg<4;reg++){
    int row = rt*16 + quad*4 + reg;
    rsv[rt][reg] = rsS[row]; mrsv[rt][reg] = mrsS[row];
  }
  float plog[2][4] = {};
#pragma unroll
  for(int ct=0; ct<4; ct++){
    int col = wv*64 + ct*16 + colL;
    float Uc = UG[col], Gc = UG[256+col], w2 = WF[O_Wc2+col];
#pragma unroll
    for(int rt=0;rt<2;rt++)
#pragma unroll
    for(int reg=0;reg<4;reg++){
      float h = rsv[rt][reg]*acc[rt][ct][reg] - mrsv[rt][reg]*Gc + Uc;
      h = fmaxf(h, 0.f);
      plog[rt][reg] = fmaf(h, w2, plog[rt][reg]);
    }
  }
#pragma unroll
  for(int o=1;o<16;o<<=1)
#pragma unroll
  for(int rt=0;rt<2;rt++)
#pragma unroll
  for(int reg=0;reg<4;reg++) plog[rt][reg] += __shfl_xor(plog[rt][reg], o);
  float* red = (float*)As;
  if(colL==0){
#pragma unroll
    for(int rt=0;rt<2;rt++)
#pragma unroll
    for(int reg=0;reg<4;reg++) red[wv*32 + rt*16 + quad*4 + reg] = plog[rt][reg];
  }
  __syncthreads();
  if(t<32){
    float l = red[t] + red[32+t] + red[64+t] + red[96+t] + WF[O_bc2];
    out[(long)blockIdx.x*32 + t] = l;
  }
}

// ---------------- workspace layout (bytes) ----------------
#define WS_MASK   3145728u
#define WS_POOLED 3211264u
#define WS_UG     3473408u
#define WS_WT     4194304u
#define WS_WTC    4980736u
#define WS_H      6291456u
#define WS_X0     14680064u
#define WS_Q      23068672u
#define WS_CTX    48234496u
#define WS_X1     56623104u
// total 73,400,320 B (~70 MiB)

extern "C" void kernel_launch(void* const* d_in, const int* in_sizes, int n_in,
                              void* d_out, int out_size, void* d_ws, size_t ws_size,
                              hipStream_t stream){
  char* ws = (char*)d_ws;
  float* WF     = (float*)ws;
  int*   maskI  = (int*)  (ws + WS_MASK);
  float* pooled = (float*)(ws + WS_POOLED);
  float* UG     = (float*)(ws + WS_UG);
  u16*   WT     = (u16*)  (ws + WS_WT);      // 6 x [256][256] bf16 (fragment-major)
  u16*   WTC    = (u16*)  (ws + WS_WTC);     // [256][1024] bf16 (fragment-major)
  u16*   hb     = (u16*)  (ws + WS_H);
  u16*   x0b    = (u16*)  (ws + WS_X0);
  u16*   qkvb   = (u16*)  (ws + WS_Q);       // 3 x [16384][256] bf16
  u16*   ctxb   = (u16*)  (ws + WS_CTX);
  float* x1     = (float*)(ws + WS_X1);

  WPar wp;
  for(int i=0;i<25;i++) wp.src[i] = d_in[4+i];
  wp.traj = (const u32*)d_in[0];
  wp.dst  = WF;

  const void* traj  = d_in[0];
  const int* roles  = (const int*)d_in[1];
  const int* pairs  = (const int*)d_in[2];
  const u32* mraw   = (const u32*)d_in[3];
  float* out = (float*)d_out;

  hipLaunchKernelGGL(k_conv,  dim3((TOTW+255)/256), dim3(256), 0, stream, wp);
  hipLaunchKernelGGL(k_pool,  dim3(256),  dim3(256), 0, stream, traj, mraw, pooled, maskI);
  hipLaunchKernelGGL(k_trans, dim3(96),   dim3(256), 0, stream, WF, WT);
  hipLaunchKernelGGL(k_transc,dim3(64),   dim3(256), 0, stream, WF, WTC);
  hipLaunchKernelGGL(k_prep,  dim3(256),  dim3(256), 0, stream, WF, UG);
  hipLaunchKernelGGL(k_h,     dim3(4096), dim3(256), 0, stream, WF, pooled, roles, (u32*)hb);
  hipLaunchKernelGGL(k_enc2,  dim3(512),  dim3(256), 0, stream, WF, hb, roles, maskI,
                     WT + 0*65536, WT + 1*65536, x0b);
  hipLaunchKernelGGL(k_qkv,   dim3(512,3),dim3(256), 0, stream, WF, x0b, WT + 2*65536, qkvb);
  hipLaunchKernelGGL(k_attn5, dim3(256,4),dim3(256), 0, stream,
                     (const u32*)qkvb, (const u32*)(qkvb+4194304), (const u32*)(qkvb+2*4194304),
                     maskI, (u32*)ctxb);
  hipLaunchKernelGGL(k_oproj, dim3(512),  dim3(256), 0, stream, WF, ctxb, x0b, WT + 5*65536, x1);
  hipLaunchKernelGGL(k_cls,   dim3(1024), dim3(256), 0, stream, WF, x1, pairs, WTC, UG, out);
}

// Round 14
// 306.003 us; speedup vs baseline: 1.1069x; 1.1069x over previous
//
#include <hip/hip_runtime.h>
#include <hip/hip_bf16.h>

typedef unsigned int u32;
typedef unsigned short u16;
typedef __attribute__((ext_vector_type(8))) short short8;   // 8 bf16 (4 VGPRs)
typedef __attribute__((ext_vector_type(4))) float f32x4;    // 4 fp32 acc

#define MFMA(a,b,c) __builtin_amdgcn_mfma_f32_16x16x32_bf16(a,b,c,0,0,0)

// ---------------- helpers ----------------
__device__ __forceinline__ float bf2f(u16 u){ return __uint_as_float(((u32)u)<<16); }
__device__ __forceinline__ float lo16(u32 w){ return __uint_as_float(w<<16); }
__device__ __forceinline__ float hi16(u32 w){ return __uint_as_float(w & 0xffff0000u); }
__device__ __forceinline__ u16 f2b(float x){ __hip_bfloat16 h=__float2bfloat16(x); return *(u16*)&h; }
__device__ __forceinline__ u32 pack2(float a, float b){ return (u32)f2b(a) | ((u32)f2b(b)<<16); }

// canonical f32 weight pool: element offsets (verified R5)
#define O_Wf1 0
#define O_bf1 1024
#define O_Wf2 1280
#define O_bf2 66816
#define O_Wu1 67072
#define O_bu1 68096
#define O_Wu2 68352
#define O_bu2 133888
#define O_remb 134144
#define O_Wq 134656
#define O_bq 200192
#define O_Wk 200448
#define O_bk 265984
#define O_Wv 266240
#define O_bv 331776
#define O_Wo 332032
#define O_bo 397568
#define O_ag 397824
#define O_ab 398080
#define O_lg 398336
#define O_lb 399616
#define O_Wc1 400896
#define O_bc1 728576
#define O_Wc2 728832
#define O_bc2 729088
#define TOTW 729089

static __device__ const int c_off[26] = {
  0,1024,1280,66816,67072,68096,68352,133888,134144,134656,200192,200448,
  265984,266240,331776,332032,397568,397824,398080,398336,399616,400896,
  728576,728832,729088,729089};

struct WPar { const void* src[25]; const u32* traj; float* dst; };

__device__ __forceinline__ int detect_bf16(const u32* traj){
  int inr = 0;
#pragma unroll 1
  for(int i=0;i<64;i++){
    u32 e = (traj[i]>>7) & 0xffu;
    inr += (e >= 0x58u && e <= 0x9au) ? 1 : 0;
  }
  return (inr==64) ? 1 : 0;
}

// ---------------- K0: canonicalize all weights to f32 (verified R5) ----------------
__global__ __launch_bounds__(256) void k_conv(WPar p){
  __shared__ int fl;
  if(threadIdx.x==0) fl = detect_bf16(p.traj);
  __syncthreads();
  int mode = fl;
  int g = blockIdx.x*256 + threadIdx.x;
  if(g >= TOTW) return;
  int t = 0;
#pragma unroll 1
  for(int i=1;i<25;i++) if(g >= c_off[i]) t = i;
  int j = g - c_off[t];
  float v = mode ? bf2f(((const u16*)p.src[t])[j]) : ((const float*)p.src[t])[j];
  p.dst[g] = v;
}

// ---------------- K1: mean-pool + mask normalize (verified R5) ----------------
__global__ __launch_bounds__(256) void k_pool(const void* __restrict__ traj, const u32* __restrict__ mraw,
                                              float* __restrict__ pooled, int* __restrict__ maskI){
  __shared__ int fl;
  if(threadIdx.x==0) fl = detect_bf16((const u32*)traj);
  __syncthreads();
  int t = blockIdx.x*256 + threadIdx.x;
  int b = t>>8, r = t&255;
  float s = 0.f;
  if(fl){
    const u16* tp = (const u16*)traj + (size_t)b*12800 + r;
#pragma unroll 1
    for(int l=0;l<50;l++) s += bf2f(tp[l*256]);
  } else {
    const float* tp = (const float*)traj + (size_t)b*12800 + r;
#pragma unroll 1
    for(int l=0;l<50;l++) s += tp[l*256];
  }
  pooled[t] = s * 0.02f;
  if(t < 16384){
    bool isByte = false;
#pragma unroll
    for(int w=0;w<16;w++) isByte |= (mraw[w] > 1u);
    int v;
    if(isByte){ u32 w = mraw[t>>2]; v = (int)((w >> ((t&3)*8)) & 0xffu); }
    else      { v = (int)mraw[t]; }
    maskI[t] = (v!=0) ? 1 : 0;
  }
}

// ---------------- K2: transpose f32 -> bf16 WT in MFMA-fragment-major order ----------------
static __device__ const int t_src[6] = {O_Wf2, O_Wu2, O_Wq, O_Wk, O_Wv, O_Wo};
__global__ __launch_bounds__(256) void k_trans(const float* __restrict__ WF, u16* __restrict__ WT){
  __shared__ float tl[64][65];
  int mat = blockIdx.x >> 4, tile = blockIdx.x & 15;
  int kt = (tile>>2)*64, nt = (tile&3)*64;
  int t = threadIdx.x;
  int i = t>>2, c4 = (t&3)*16;
  const float* src = WF + t_src[mat] + (kt+i)*256 + nt + c4;
#pragma unroll
  for(int c=0;c<16;c+=4) *(float4*)&tl[i][c4+c] = *(const float4*)(src + c);
  __syncthreads();
  int n = nt + i;
  int tile_n = n >> 4, nl = n & 15;
  int ks = (kt + c4) >> 5;
  u16* base = WT + mat*65536;
#pragma unroll
  for(int h=0; h<2; h++){
    int quad = ((c4 + h*8) >> 3) & 3;
    short8 v;
#pragma unroll
    for(int j=0;j<8;j++) v[j] = (short)f2b(tl[c4 + h*8 + j][i]);
    *(short8*)(base + ((tile_n*8 + ks)*64 + quad*16 + nl)*8) = v;
  }
}

// ---------------- K3: WTC (lg-folded, d-combined Wc1^T, K=1024) in fragment-major order ----------------
__global__ __launch_bounds__(256) void k_transc(const float* __restrict__ WF, u16* __restrict__ WTC){
  __shared__ float tl[64][65];
  int seg = blockIdx.x >> 4, tile = blockIdx.x & 15;
  int jt = (tile>>2)*64, nt = (tile&3)*64;
  int t = threadIdx.x;
  int i = t>>2, c4 = (t&3)*16;
  int j = jt + i;
#pragma unroll 1
  for(int c=0;c<16;c++){
    int n = nt + c4 + c;
    float v;
    if(seg==0)      v = WF[O_lg+j]*WF[O_Wc1 + j*256 + n] + WF[O_lg+768+j]*WF[O_Wc1 + (768+j)*256 + n];
    else if(seg==1) v = WF[O_lg+256+j]*WF[O_Wc1+(256+j)*256+n] - WF[O_lg+768+j]*WF[O_Wc1+(768+j)*256+n];
    else if(seg==2) v = WF[O_lg+512+j]*WF[O_Wc1+(512+j)*256+n];
    else            v = WF[O_lg+1024+j]*WF[O_Wc1+(1024+j)*256+n];
    tl[i][c4+c] = v;
  }
  __syncthreads();
  int n = nt + i;
  int tile_n = n >> 4, nl = n & 15;
  int kbase = seg*256 + jt + c4;
  int ks = kbase >> 5;
#pragma unroll
  for(int h=0; h<2; h++){
    int quad = ((kbase + h*8) >> 3) & 3;
    short8 v;
#pragma unroll
    for(int jj=0;jj<8;jj++) v[jj] = (short)f2b(tl[c4 + h*8 + jj][i]);
    *(short8*)(WTC + ((tile_n*32 + ks)*64 + quad*16 + nl)*8) = v;
  }
}

// ---------------- K4: U[n] = sum lb*Wc1 + bc1 ; G[n] = sum lg*Wc1 (grid=256) ----------------
__global__ __launch_bounds__(256) void k_prep(const float* __restrict__ WF, float* __restrict__ UG){
  __shared__ float ru[4], rg[4];
  int n = blockIdx.x;
  int t = threadIdx.x;
  float u = 0.f, g = 0.f;
#pragma unroll
  for(int j=0;j<5;j++){
    int m = t + j*256;
    float w = WF[O_Wc1 + m*256 + n];
    u = fmaf(WF[O_lb+m], w, u);
    g = fmaf(WF[O_lg+m], w, g);
  }
#pragma unroll
  for(int o=32;o>0;o>>=1){ u += __shfl_xor(u,o,64); g += __shfl_xor(g,o,64); }
  int wv = t>>6;
  if((t&63)==0){ ru[wv]=u; rg[wv]=g; }
  __syncthreads();
  if(t==0){
    UG[n]     = ru[0]+ru[1]+ru[2]+ru[3] + WF[O_bc1+n];
    UG[256+n] = rg[0]+rg[1]+rg[2]+rg[3];
  }
}

// ---------------- K5: enc layer 1 -> h bf16 [16384][256] ----------------
__global__ __launch_bounds__(256) void k_h(const float* __restrict__ WF, const float* __restrict__ pooled,
                                           const int* __restrict__ roles, u32* __restrict__ hb){
  int g = blockIdx.x*256 + threadIdx.x;       // 1,048,576 total, 4 elems each
  int r = g>>6, e0 = (g&63)*4;
  float4 pl = *(const float4*)(pooled + r*4);
  int role = roles[r];
  const float* W1 = WF + (role ? O_Wu1 : O_Wf1);
  const float* b1 = WF + (role ? O_bu1 : O_bf1);
  float h[4];
#pragma unroll
  for(int c=0;c<4;c++){
    int e = e0+c;
    float v = b1[e] + pl.x*W1[e] + pl.y*W1[256+e] + pl.z*W1[512+e] + pl.w*W1[768+e];
    h[c] = fmaxf(v, 0.f);
  }
  hb[(r*256+e0)>>1]     = pack2(h[0],h[1]);
  hb[((r*256+e0)>>1)+1] = pack2(h[2],h[3]);
}

// ---------------- shared GEMM pieces (BM=32, K=256, LDS stride 264) ----------------
__device__ __forceinline__ void stageA256(const u16* __restrict__ A, long row0, u16* As){
  int t = threadIdx.x;
  int r = t >> 3, c0 = (t & 7) * 32;
  const u16* src = A + (row0 + r)*256 + c0;
  u16* dst = As + r*264 + c0;
#pragma unroll
  for(int i=0;i<4;i++) *(short8*)(dst + i*8) = *(const short8*)(src + i*8);
}

// B in fragment-major order: frag(tile,ks) at ((tile*8+ks)*64 + lane)*8 — 1KB coalesced/wave
__device__ __forceinline__ void mmK256(const u16* As, const u16* __restrict__ WT, int wv,
                                       int colL, int quad, int lane, f32x4 acc[2][4]){
#pragma unroll
  for(int ks=0; ks<8; ks++){
    short8 a0 = *(short8*)(As + colL*264 + ks*32 + quad*8);
    short8 a1 = *(short8*)(As + (colL+16)*264 + ks*32 + quad*8);
#pragma unroll
    for(int ct=0; ct<4; ct++){
      short8 b = *(const short8*)(WT + (((wv*4+ct)*8 + ks)*64 + lane)*8);
      acc[0][ct] = MFMA(a0, b, acc[0][ct]);
      acc[1][ct] = MFMA(a1, b, acc[1][ct]);
    }
  }
}

// ---------------- K6: enc layer 2 dual GEMM + select + mask + remb -> x0 bf16 ----------------
__global__ __launch_bounds__(256,2) void k_enc2(const float* __restrict__ WF, const u16* __restrict__ hb,
                                                const int* __restrict__ roles, const int* __restrict__ maskI,
                                                const u16* __restrict__ WT2F, const u16* __restrict__ WT2U,
                                                u16* __restrict__ x0b){
  __shared__ u16 As[32*264];
  __shared__ int roleS[32], maskS[32];
  long row0 = (long)blockIdx.x*32;
  int t = threadIdx.x;
  stageA256(hb, row0, As);
  if(t<32){ roleS[t]=roles[row0+t]; maskS[t]=maskI[row0+t]; }
  __syncthreads();
  int lane = t & 63, wv = t >> 6;
  int colL = lane & 15, quad = lane >> 4;
  f32x4 accF[2][4] = {};
  f32x4 accU[2][4] = {};
  mmK256(As, WT2F, wv, colL, quad, lane, accF);
  mmK256(As, WT2U, wv, colL, quad, lane, accU);
#pragma unroll
  for(int ct=0; ct<4; ct++){
    int col = wv*64 + ct*16 + colL;
    float bfc = WF[O_bf2+col], buc = WF[O_bu2+col];
    float r0c = WF[O_remb+col], r1c = WF[O_remb+256+col];
#pragma unroll
    for(int rt=0; rt<2; rt++)
#pragma unroll
    for(int reg=0; reg<4; reg++){
      int row = rt*16 + quad*4 + reg;
      float vf = accF[rt][ct][reg] + bfc;
      float vu = accU[rt][ct][reg] + buc;
      int ro = roleS[row];
      float v = ro ? vu : vf;
      v = maskS[row] ? v : 0.f;
      v += ro ? r1c : r0c;
      x0b[(size_t)(row0+row)*256 + col] = f2b(v);
    }
  }
}

// ---------------- K7: fused q/k/v GEMM — stage A once, loop y (R14 experiment) ----------------
static __device__ const int qkv_b[3] = {O_bq, O_bk, O_bv};
__global__ __launch_bounds__(256,2) void k_qkv3(const float* __restrict__ WF, const u16* __restrict__ x0b,
                                                const u16* __restrict__ WTQKV, u16* __restrict__ qout){
  __shared__ u16 As[32*264];
  long row0 = (long)blockIdx.x*32;
  stageA256(x0b, row0, As);
  __syncthreads();
  int t = threadIdx.x;
  int lane = t & 63, wv = t >> 6;
  int colL = lane & 15, quad = lane >> 4;
#pragma unroll 1
  for(int y=0; y<3; y++){
    f32x4 acc[2][4] = {};
    mmK256(As, WTQKV + y*65536, wv, colL, quad, lane, acc);
    u16* outp = qout + (size_t)y*4194304;
    int bo = qkv_b[y];
#pragma unroll
    for(int ct=0; ct<4; ct++){
      int col = wv*64 + ct*16 + colL;
      float bc = WF[bo+col];
#pragma unroll
      for(int rt=0; rt<2; rt++)
#pragma unroll
      for(int reg=0; reg<4; reg++){
        int row = rt*16 + quad*4 + reg;
        outp[(size_t)(row0+row)*256 + col] = f2b(acc[rt][ct][reg] + bc);
      }
    }
  }
}

// ---------------- K8: attention, spill-free split (verified R12) ----------------
__global__ __launch_bounds__(256,1) void k_attn5(const u32* __restrict__ qb, const u32* __restrict__ kb,
                                                 const u32* __restrict__ vb, const int* __restrict__ maskI,
                                                 u32* __restrict__ ctxb){
  __shared__ uint4 Ks4[64*8], Vs4[64*8];
  __shared__ float Ps[64*68];
  __shared__ int maskS[64];
  const int t = threadIdx.x;
  const int b = blockIdx.x, h = blockIdx.y;
  {
    int r = t>>2, c2 = (t&3)*2;
    size_t g = (size_t)(b*64+r)*128 + h*32;
    const uint4* kr = (const uint4*)(kb + g);
    const uint4* vr = (const uint4*)(vb + g);
    int rot = r + (r>>4);
#pragma unroll
    for(int i=0;i<2;i++){
      int c = c2 + i;
      int pc = (c + rot) & 7;
      Ks4[r*8 + pc] = kr[c];
      Vs4[r*8 + pc] = vr[c];
    }
    if(t<64) maskS[t] = maskI[b*64+t];
  }
  const int lane = t & 63;
  const int wv = __builtin_amdgcn_readfirstlane(t>>6);
  const int qq = lane>>2, part = lane&3;
  const int q = wv*16 + qq;
  uint4 qp[8];                                  // packed Q: 32 VGPRs
  {
    const uint4* qr = (const uint4*)(qb + (size_t)(b*64+q)*128 + h*32);
#pragma unroll
    for(int c=0;c<8;c++) qp[c] = qr[c];
  }
  __syncthreads();
  float s[16];
#pragma unroll 1
  for(int jj=0;jj<16;jj++){
    int j = part*16 + jj;
    int rot = j + (j>>4);
    const uint4* kr = Ks4 + j*8;
    float d0=0.f, d1=0.f;
#pragma unroll
    for(int c=0;c<8;c++){
      uint4 w = kr[(c + rot) & 7];
      uint4 qw = qp[c];
      d0 = fmaf(lo16(qw.x), lo16(w.x), d0);
      d1 = fmaf(hi16(qw.x), hi16(w.x), d1);
      d0 = fmaf(lo16(qw.y), lo16(w.y), d0);
      d1 = fmaf(hi16(qw.y), hi16(w.y), d1);
      d0 = fmaf(lo16(qw.z), lo16(w.z), d0);
      d1 = fmaf(hi16(qw.z), hi16(w.z), d1);
      d0 = fmaf(lo16(qw.w), lo16(w.w), d0);
      d1 = fmaf(hi16(qw.w), hi16(w.w), d1);
    }
    s[jj] = maskS[j] ? (d0+d1)*0.125f : -1e9f;
  }
  float mx = s[0];
#pragma unroll
  for(int jj=1;jj<16;jj++) mx = fmaxf(mx, s[jj]);
  mx = fmaxf(mx, __shfl_xor(mx,1,64));
  mx = fmaxf(mx, __shfl_xor(mx,2,64));
  float sum = 0.f;
#pragma unroll
  for(int jj=0;jj<16;jj++){ s[jj] = __expf(s[jj]-mx); sum += s[jj]; }
  sum += __shfl_xor(sum,1,64);
  sum += __shfl_xor(sum,2,64);
  float inv = 1.f/sum;
#pragma unroll
  for(int jj=0;jj<16;jj++) Ps[q*68 + part*16 + jj] = s[jj]*inv;
  __syncthreads();
  float cx[16];
#pragma unroll
  for(int c=0;c<16;c++) cx[c]=0.f;
#pragma unroll 2
  for(int j=0;j<64;j++){
    float p = Ps[q*68 + j];
    int rot = j + (j>>4);
    const uint4* vr = Vs4 + j*8;
    uint4 w0 = vr[(part*2 + rot) & 7];
    uint4 w1 = vr[(part*2 + 1 + rot) & 7];
    cx[0] = fmaf(p, lo16(w0.x), cx[0]);  cx[1] = fmaf(p, hi16(w0.x), cx[1]);
    cx[2] = fmaf(p, lo16(w0.y), cx[2]);  cx[3] = fmaf(p, hi16(w0.y), cx[3]);
    cx[4] = fmaf(p, lo16(w0.z), cx[4]);  cx[5] = fmaf(p, hi16(w0.z), cx[5]);
    cx[6] = fmaf(p, lo16(w0.w), cx[6]);  cx[7] = fmaf(p, hi16(w0.w), cx[7]);
    cx[8] = fmaf(p, lo16(w1.x), cx[8]);  cx[9] = fmaf(p, hi16(w1.x), cx[9]);
    cx[10]= fmaf(p, lo16(w1.y), cx[10]); cx[11]= fmaf(p, hi16(w1.y), cx[11]);
    cx[12]= fmaf(p, lo16(w1.z), cx[12]); cx[13]= fmaf(p, hi16(w1.z), cx[13]);
    cx[14]= fmaf(p, lo16(w1.w), cx[14]); cx[15]= fmaf(p, hi16(w1.w), cx[15]);
  }
  u32 ow[8];
#pragma unroll
  for(int i=0;i<8;i++) ow[i] = pack2(cx[2*i], cx[2*i+1]);
  u32* orow = ctxb + (size_t)(b*64+q)*128 + h*32 + part*8;
  *(uint4*)(orow)     = make_uint4(ow[0],ow[1],ow[2],ow[3]);
  *(uint4*)(orow + 4) = make_uint4(ow[4],ow[5],ow[6],ow[7]);
}

// ---------------- K9: oproj GEMM + residual + LN -> x1 f32 ----------------
__global__ __launch_bounds__(256,2) void k_oproj(const float* __restrict__ WF, const u16* __restrict__ ctxb,
                                                 const u16* __restrict__ x0b, const u16* __restrict__ WTO,
                                                 float* __restrict__ x1){
  __shared__ u16 As[32*264];
  __shared__ float Sred[4][32], Qred[4][32], Mrow[32], Rrow[32];
  long row0 = (long)blockIdx.x*32;
  stageA256(ctxb, row0, As);
  __syncthreads();
  int t = threadIdx.x;
  int lane = t & 63, wv = t >> 6;
  int colL = lane & 15, quad = lane >> 4;
  f32x4 acc[2][4] = {};
  mmK256(As, WTO, wv, colL, quad, lane, acc);
  float S[2][4] = {}, Q[2][4] = {};
#pragma unroll
  for(int ct=0; ct<4; ct++){
    int col = wv*64 + ct*16 + colL;
    float bc = WF[O_bo+col];
#pragma unroll
    for(int rt=0; rt<2; rt++)
#pragma unroll
    for(int reg=0; reg<4; reg++){
      int row = rt*16 + quad*4 + reg;
      float y = acc[rt][ct][reg] + bc + bf2f(x0b[(size_t)(row0+row)*256 + col]);
      acc[rt][ct][reg] = y;
      S[rt][reg] += y; Q[rt][reg] += y*y;
    }
  }
#pragma unroll
  for(int o=1;o<16;o<<=1)
#pragma unroll
  for(int rt=0;rt<2;rt++)
#pragma unroll
  for(int reg=0;reg<4;reg++){ S[rt][reg] += __shfl_xor(S[rt][reg],o); Q[rt][reg] += __shfl_xor(Q[rt][reg],o); }
  if(colL==0){
#pragma unroll
    for(int rt=0;rt<2;rt++)
#pragma unroll
    for(int reg=0;reg<4;reg++){
      Sred[wv][rt*16+quad*4+reg] = S[rt][reg];
      Qred[wv][rt*16+quad*4+reg] = Q[rt][reg];
    }
  }
  __syncthreads();
  if(t<32){
    float s = Sred[0][t]+Sred[1][t]+Sred[2][t]+Sred[3][t];
    float q = Qred[0][t]+Qred[1][t]+Qred[2][t]+Qred[3][t];
    float mean = s*(1.f/256.f);
    float var  = q*(1.f/256.f) - mean*mean;
    Mrow[t] = mean; Rrow[t] = rsqrtf(var + 1e-5f);
  }
  __syncthreads();
#pragma unroll
  for(int ct=0; ct<4; ct++){
    int col = wv*64 + ct*16 + colL;
    float gc = WF[O_ag+col], bc = WF[O_ab+col];
#pragma unroll
    for(int rt=0; rt<2; rt++)
#pragma unroll
    for(int reg=0; reg<4; reg++){
      int row = rt*16 + quad*4 + reg;
      x1[(size_t)(row0+row)*256 + col] = (acc[rt][ct][reg]-Mrow[row])*Rrow[row]*gc + bc;
    }
  }
}

// ---------------- K10: per-pair LN stats over 1280 rel features (verified R12) ----------------
__global__ __launch_bounds__(256) void k_stats(const float* __restrict__ x1, const int* __restrict__ pairs,
                                               float* __restrict__ rsG, float* __restrict__ mrsG){
  int t = threadIdx.x;
  int r = t>>3, t8 = t&7;
  long pr = (long)blockIdx.x*32 + r;
  int b = (int)(pr>>7);
  int i0 = pairs[pr*2], i1 = pairs[pr*2+1];
  const float* ef = x1 + (size_t)(b*64+i0)*256 + t8*32;
  const float* eu = x1 + (size_t)(b*64+i1)*256 + t8*32;
  float S=0.f, Q=0.f;
#pragma unroll
  for(int c=0;c<32;c+=4){
    float4 e4 = *(const float4*)(ef+c);
    float4 u4 = *(const float4*)(eu+c);
    float e[4]={e4.x,e4.y,e4.z,e4.w}, u[4]={u4.x,u4.y,u4.z,u4.w};
#pragma unroll
    for(int j=0;j<4;j++){
      float d = e[j]-u[j], p = e[j]*u[j];
      S += 2.f*e[j] + fabsf(d) + p;
      Q += e[j]*e[j] + u[j]*u[j] + 2.f*d*d + p*p;
    }
  }
#pragma unroll
  for(int o=1;o<8;o<<=1){ S += __shfl_xor(S,o); Q += __shfl_xor(Q,o); }
  if(t8==0){
    float mean = S*(1.f/1280.f);
    float var  = Q*(1.f/1280.f) - mean*mean;
    float rs = rsqrtf(var + 1e-5f);
    rsG[pr] = rs; mrsG[pr] = mean*rs;
  }
}

// ---------------- K11: classifier GEMM, 2-pass K-split (32 KB LDS) — verified R12 ----------------
__global__ __launch_bounds__(256) void k_cls(const float* __restrict__ WF, const float* __restrict__ x1,
                                             const int* __restrict__ pairs, const u16* __restrict__ WTC,
                                             const float* __restrict__ UG, const float* __restrict__ rsG,
                                             const float* __restrict__ mrsG, float* __restrict__ out){
  __shared__ u16 As[32*512];                   // 32 KB; XOR-swizzled chunks of 8
  int t = threadIdx.x;
  int lane = t & 63, wv = t >> 6;
  int colL = lane & 15, quad = lane >> 4;
  int rxl = colL & 7;
  int r = t>>3, t8 = t&7, rx = r&7;
  long pr = (long)blockIdx.x*32 + r;
  int bb = (int)(pr>>7);
  int i0 = pairs[pr*2], i1 = pairs[pr*2+1];
  const float* ef = x1 + (size_t)(bb*64+i0)*256 + t8*32;
  const float* eu = x1 + (size_t)(bb*64+i1)*256 + t8*32;
  f32x4 acc[2][4] = {};
#pragma unroll 1
  for(int pass=0; pass<2; pass++){
#pragma unroll
    for(int c=0;c<4;c++){
      float e[8], u[8];
      *(float4*)(e)   = *(const float4*)(ef + c*8);
      *(float4*)(e+4) = *(const float4*)(ef + c*8 + 4);
      *(float4*)(u)   = *(const float4*)(eu + c*8);
      *(float4*)(u+4) = *(const float4*)(eu + c*8 + 4);
      short8 f0, f1;
#pragma unroll
      for(int j=0;j<8;j++){
        float d = e[j]-u[j];
        if(pass==0){ f0[j] = (short)f2b(e[j]);        f1[j] = (short)f2b(u[j]); }
        else       { f0[j] = (short)f2b(fabsf(d));    f1[j] = (short)f2b(e[j]*u[j]); }
      }
      int cc = t8*4 + c;
      *(short8*)(As + r*512 + (( 0 + cc)^rx)*8) = f0;
      *(short8*)(As + r*512 + ((32 + cc)^rx)*8) = f1;
    }
    __syncthreads();
#pragma unroll 1
    for(int ks=0; ks<16; ks++){
      short8 a0 = *(short8*)(As + colL*512      + ((ks*4+quad)^rxl)*8);
      short8 a1 = *(short8*)(As + (colL+16)*512 + ((ks*4+quad)^rxl)*8);
      int kst = pass*16 + ks;
#pragma unroll
      for(int ct=0;ct<4;ct++){
        short8 b = *(const short8*)(WTC + (size_t)(((wv*4+ct)*32 + kst)*64 + lane)*8);
        acc[0][ct] = MFMA(a0, b, acc[0][ct]);
        acc[1][ct] = MFMA(a1, b, acc[1][ct]);
      }
    }
    __syncthreads();
  }
  float rsv[2][4], mrsv[2][4];
#pragma unroll
  for(int rt=0;rt<2;rt++)
#pragma unroll
  for(int reg=0;reg<4;reg++){
    long grow = (long)blockIdx.x*32 + rt*16 + quad*4 + reg;
    rsv[rt][reg] = rsG[grow]; mrsv[rt][reg] = mrsG[grow];
  }
  float plog[2][4] = {};
#pragma unroll
  for(int ct=0; ct<4; ct++){
    int col = wv*64 + ct*16 + colL;
    float Uc = UG[col], Gc = UG[256+col], w2 = WF[O_Wc2+col];
#pragma unroll
    for(int rt=0;rt<2;rt++)
#pragma unroll
    for(int reg=0;reg<4;reg++){
      float h = rsv[rt][reg]*acc[rt][ct][reg] - mrsv[rt][reg]*Gc + Uc;
      h = fmaxf(h, 0.f);
      plog[rt][reg] = fmaf(h, w2, plog[rt][reg]);
    }
  }
#pragma unroll
  for(int o=1;o<16;o<<=1)
#pragma unroll
  for(int rt=0;rt<2;rt++)
#pragma unroll
  for(int reg=0;reg<4;reg++) plog[rt][reg] += __shfl_xor(plog[rt][reg], o);
  float* red = (float*)As;
  if(colL==0){
#pragma unroll
    for(int rt=0;rt<2;rt++)
#pragma unroll
    for(int reg=0;reg<4;reg++) red[wv*32 + rt*16 + quad*4 + reg] = plog[rt][reg];
  }
  __syncthreads();
  if(t<32){
    float l = red[t] + red[32+t] + red[64+t] + red[96+t] + WF[O_bc2];
    out[(long)blockIdx.x*32 + t] = l;
  }
}

// ---------------- workspace layout (bytes) ----------------
#define WS_MASK   3145728u
#define WS_POOLED 3211264u
#define WS_UG     3473408u
#define WS_RS     3475456u
#define WS_MRS    3606528u
#define WS_WT     4194304u
#define WS_WTC    4980736u
#define WS_H      6291456u
#define WS_X0     14680064u
#define WS_Q      23068672u
#define WS_CTX    48234496u
#define WS_X1     56623104u
// total 73,400,320 B (~70 MiB)

extern "C" void kernel_launch(void* const* d_in, const int* in_sizes, int n_in,
                              void* d_out, int out_size, void* d_ws, size_t ws_size,
                              hipStream_t stream){
  char* ws = (char*)d_ws;
  float* WF     = (float*)ws;
  int*   maskI  = (int*)  (ws + WS_MASK);
  float* pooled = (float*)(ws + WS_POOLED);
  float* UG     = (float*)(ws + WS_UG);
  float* rsG    = (float*)(ws + WS_RS);
  float* mrsG   = (float*)(ws + WS_MRS);
  u16*   WT     = (u16*)  (ws + WS_WT);      // 6 x [256][256] bf16 (fragment-major)
  u16*   WTC    = (u16*)  (ws + WS_WTC);     // [256][1024] bf16 (fragment-major)
  u16*   hb     = (u16*)  (ws + WS_H);
  u16*   x0b    = (u16*)  (ws + WS_X0);
  u16*   qkvb   = (u16*)  (ws + WS_Q);       // 3 x [16384][256] bf16
  u16*   ctxb   = (u16*)  (ws + WS_CTX);
  float* x1     = (float*)(ws + WS_X1);

  WPar wp;
  for(int i=0;i<25;i++) wp.src[i] = d_in[4+i];
  wp.traj = (const u32*)d_in[0];
  wp.dst  = WF;

  const void* traj  = d_in[0];
  const int* roles  = (const int*)d_in[1];
  const int* pairs  = (const int*)d_in[2];
  const u32* mraw   = (const u32*)d_in[3];
  float* out = (float*)d_out;

  hipLaunchKernelGGL(k_conv,  dim3((TOTW+255)/256), dim3(256), 0, stream, wp);
  hipLaunchKernelGGL(k_pool,  dim3(256),  dim3(256), 0, stream, traj, mraw, pooled, maskI);
  hipLaunchKernelGGL(k_trans, dim3(96),   dim3(256), 0, stream, WF, WT);
  hipLaunchKernelGGL(k_transc,dim3(64),   dim3(256), 0, stream, WF, WTC);
  hipLaunchKernelGGL(k_prep,  dim3(256),  dim3(256), 0, stream, WF, UG);
  hipLaunchKernelGGL(k_h,     dim3(4096), dim3(256), 0, stream, WF, pooled, roles, (u32*)hb);
  hipLaunchKernelGGL(k_enc2,  dim3(512),  dim3(256), 0, stream, WF, hb, roles, maskI,
                     WT + 0*65536, WT + 1*65536, x0b);
  hipLaunchKernelGGL(k_qkv3,  dim3(512),  dim3(256), 0, stream, WF, x0b, WT + 2*65536, qkvb);
  hipLaunchKernelGGL(k_attn5, dim3(256,4),dim3(256), 0, stream,
                     (const u32*)qkvb, (const u32*)(qkvb+4194304), (const u32*)(qkvb+2*4194304),
                     maskI, (u32*)ctxb);
  hipLaunchKernelGGL(k_oproj, dim3(512),  dim3(256), 0, stream, WF, ctxb, x0b, WT + 5*65536, x1);
  hipLaunchKernelGGL(k_stats, dim3(1024), dim3(256), 0, stream, x1, pairs, rsG, mrsG);
  hipLaunchKernelGGL(k_cls,   dim3(1024), dim3(256), 0, stream, WF, x1, pairs, WTC, UG, rsG, mrsG, out);
}

// Round 15
// 282.916 us; speedup vs baseline: 1.1972x; 1.0816x over previous
//
#include <hip/hip_runtime.h>
#include <hip/hip_bf16.h>

typedef unsigned int u32;
typedef unsigned short u16;
typedef __attribute__((ext_vector_type(8))) short short8;   // 8 bf16 (4 VGPRs)
typedef __attribute__((ext_vector_type(4))) float f32x4;    // 4 fp32 acc

#define MFMA(a,b,c) __builtin_amdgcn_mfma_f32_16x16x32_bf16(a,b,c,0,0,0)

// ---------------- helpers ----------------
__device__ __forceinline__ float bf2f(u16 u){ return __uint_as_float(((u32)u)<<16); }
__device__ __forceinline__ float lo16(u32 w){ return __uint_as_float(w<<16); }
__device__ __forceinline__ float hi16(u32 w){ return __uint_as_float(w & 0xffff0000u); }
__device__ __forceinline__ u16 f2b(float x){ __hip_bfloat16 h=__float2bfloat16(x); return *(u16*)&h; }
__device__ __forceinline__ u32 pack2(float a, float b){ return (u32)f2b(a) | ((u32)f2b(b)<<16); }

// canonical f32 weight pool: element offsets (verified R5)
#define O_Wf1 0
#define O_bf1 1024
#define O_Wf2 1280
#define O_bf2 66816
#define O_Wu1 67072
#define O_bu1 68096
#define O_Wu2 68352
#define O_bu2 133888
#define O_remb 134144
#define O_Wq 134656
#define O_bq 200192
#define O_Wk 200448
#define O_bk 265984
#define O_Wv 266240
#define O_bv 331776
#define O_Wo 332032
#define O_bo 397568
#define O_ag 397824
#define O_ab 398080
#define O_lg 398336
#define O_lb 399616
#define O_Wc1 400896
#define O_bc1 728576
#define O_Wc2 728832
#define O_bc2 729088
#define TOTW 729089

static __device__ const int c_off[26] = {
  0,1024,1280,66816,67072,68096,68352,133888,134144,134656,200192,200448,
  265984,266240,331776,332032,397568,397824,398080,398336,399616,400896,
  728576,728832,729088,729089};

struct WPar { const void* src[25]; const u32* traj; float* dst; };

__device__ __forceinline__ int detect_bf16(const u32* traj){
  int inr = 0;
#pragma unroll 1
  for(int i=0;i<64;i++){
    u32 e = (traj[i]>>7) & 0xffu;
    inr += (e >= 0x58u && e <= 0x9au) ? 1 : 0;
  }
  return (inr==64) ? 1 : 0;
}

// ---------------- K0: canonicalize all weights to f32 (verified R5) ----------------
__global__ __launch_bounds__(256) void k_conv(WPar p){
  __shared__ int fl;
  if(threadIdx.x==0) fl = detect_bf16(p.traj);
  __syncthreads();
  int mode = fl;
  int g = blockIdx.x*256 + threadIdx.x;
  if(g >= TOTW) return;
  int t = 0;
#pragma unroll 1
  for(int i=1;i<25;i++) if(g >= c_off[i]) t = i;
  int j = g - c_off[t];
  float v = mode ? bf2f(((const u16*)p.src[t])[j]) : ((const float*)p.src[t])[j];
  p.dst[g] = v;
}

// ---------------- K1: mean-pool + mask normalize (verified R5) ----------------
__global__ __launch_bounds__(256) void k_pool(const void* __restrict__ traj, const u32* __restrict__ mraw,
                                              float* __restrict__ pooled, int* __restrict__ maskI){
  __shared__ int fl;
  if(threadIdx.x==0) fl = detect_bf16((const u32*)traj);
  __syncthreads();
  int t = blockIdx.x*256 + threadIdx.x;
  int b = t>>8, r = t&255;
  float s = 0.f;
  if(fl){
    const u16* tp = (const u16*)traj + (size_t)b*12800 + r;
#pragma unroll 1
    for(int l=0;l<50;l++) s += bf2f(tp[l*256]);
  } else {
    const float* tp = (const float*)traj + (size_t)b*12800 + r;
#pragma unroll 1
    for(int l=0;l<50;l++) s += tp[l*256];
  }
  pooled[t] = s * 0.02f;
  if(t < 16384){
    bool isByte = false;
#pragma unroll
    for(int w=0;w<16;w++) isByte |= (mraw[w] > 1u);
    int v;
    if(isByte){ u32 w = mraw[t>>2]; v = (int)((w >> ((t&3)*8)) & 0xffu); }
    else      { v = (int)mraw[t]; }
    maskI[t] = (v!=0) ? 1 : 0;
  }
}

// ---------------- K2: transpose f32 -> bf16 WT in MFMA-fragment-major order ----------------
static __device__ const int t_src[6] = {O_Wf2, O_Wu2, O_Wq, O_Wk, O_Wv, O_Wo};
__global__ __launch_bounds__(256) void k_trans(const float* __restrict__ WF, u16* __restrict__ WT){
  __shared__ float tl[64][65];
  int mat = blockIdx.x >> 4, tile = blockIdx.x & 15;
  int kt = (tile>>2)*64, nt = (tile&3)*64;
  int t = threadIdx.x;
  int i = t>>2, c4 = (t&3)*16;
  const float* src = WF + t_src[mat] + (kt+i)*256 + nt + c4;
#pragma unroll
  for(int c=0;c<16;c+=4) *(float4*)&tl[i][c4+c] = *(const float4*)(src + c);
  __syncthreads();
  int n = nt + i;
  int tile_n = n >> 4, nl = n & 15;
  int ks = (kt + c4) >> 5;
  u16* base = WT + mat*65536;
#pragma unroll
  for(int h=0; h<2; h++){
    int quad = ((c4 + h*8) >> 3) & 3;
    short8 v;
#pragma unroll
    for(int j=0;j<8;j++) v[j] = (short)f2b(tl[c4 + h*8 + j][i]);
    *(short8*)(base + ((tile_n*8 + ks)*64 + quad*16 + nl)*8) = v;
  }
}

// ---------------- K3: WTC (lg-folded, d-combined Wc1^T, K=1024) in fragment-major order ----------------
__global__ __launch_bounds__(256) void k_transc(const float* __restrict__ WF, u16* __restrict__ WTC){
  __shared__ float tl[64][65];
  int seg = blockIdx.x >> 4, tile = blockIdx.x & 15;
  int jt = (tile>>2)*64, nt = (tile&3)*64;
  int t = threadIdx.x;
  int i = t>>2, c4 = (t&3)*16;
  int j = jt + i;
#pragma unroll 1
  for(int c=0;c<16;c++){
    int n = nt + c4 + c;
    float v;
    if(seg==0)      v = WF[O_lg+j]*WF[O_Wc1 + j*256 + n] + WF[O_lg+768+j]*WF[O_Wc1 + (768+j)*256 + n];
    else if(seg==1) v = WF[O_lg+256+j]*WF[O_Wc1+(256+j)*256+n] - WF[O_lg+768+j]*WF[O_Wc1+(768+j)*256+n];
    else if(seg==2) v = WF[O_lg+512+j]*WF[O_Wc1+(512+j)*256+n];
    else            v = WF[O_lg+1024+j]*WF[O_Wc1+(1024+j)*256+n];
    tl[i][c4+c] = v;
  }
  __syncthreads();
  int n = nt + i;
  int tile_n = n >> 4, nl = n & 15;
  int kbase = seg*256 + jt + c4;
  int ks = kbase >> 5;
#pragma unroll
  for(int h=0; h<2; h++){
    int quad = ((kbase + h*8) >> 3) & 3;
    short8 v;
#pragma unroll
    for(int jj=0;jj<8;jj++) v[jj] = (short)f2b(tl[c4 + h*8 + jj][i]);
    *(short8*)(WTC + ((tile_n*32 + ks)*64 + quad*16 + nl)*8) = v;
  }
}

// ---------------- K4: U[n] = sum lb*Wc1 + bc1 ; G[n] = sum lg*Wc1 (grid=256) ----------------
__global__ __launch_bounds__(256) void k_prep(const float* __restrict__ WF, float* __restrict__ UG){
  __shared__ float ru[4], rg[4];
  int n = blockIdx.x;
  int t = threadIdx.x;
  float u = 0.f, g = 0.f;
#pragma unroll
  for(int j=0;j<5;j++){
    int m = t + j*256;
    float w = WF[O_Wc1 + m*256 + n];
    u = fmaf(WF[O_lb+m], w, u);
    g = fmaf(WF[O_lg+m], w, g);
  }
#pragma unroll
  for(int o=32;o>0;o>>=1){ u += __shfl_xor(u,o,64); g += __shfl_xor(g,o,64); }
  int wv = t>>6;
  if((t&63)==0){ ru[wv]=u; rg[wv]=g; }
  __syncthreads();
  if(t==0){
    UG[n]     = ru[0]+ru[1]+ru[2]+ru[3] + WF[O_bc1+n];
    UG[256+n] = rg[0]+rg[1]+rg[2]+rg[3];
  }
}

// ---------------- K5: enc layer 1 -> h bf16 [16384][256] ----------------
__global__ __launch_bounds__(256) void k_h(const float* __restrict__ WF, const float* __restrict__ pooled,
                                           const int* __restrict__ roles, u32* __restrict__ hb){
  int g = blockIdx.x*256 + threadIdx.x;       // 1,048,576 total, 4 elems each
  int r = g>>6, e0 = (g&63)*4;
  float4 pl = *(const float4*)(pooled + r*4);
  int role = roles[r];
  const float* W1 = WF + (role ? O_Wu1 : O_Wf1);
  const float* b1 = WF + (role ? O_bu1 : O_bf1);
  float h[4];
#pragma unroll
  for(int c=0;c<4;c++){
    int e = e0+c;
    float v = b1[e] + pl.x*W1[e] + pl.y*W1[256+e] + pl.z*W1[512+e] + pl.w*W1[768+e];
    h[c] = fmaxf(v, 0.f);
  }
  hb[(r*256+e0)>>1]     = pack2(h[0],h[1]);
  hb[((r*256+e0)>>1)+1] = pack2(h[2],h[3]);
}

// ---------------- shared GEMM pieces (BM=32, K=256, LDS stride 264) ----------------
__device__ __forceinline__ void stageA256(const u16* __restrict__ A, long row0, u16* As){
  int t = threadIdx.x;
  int r = t >> 3, c0 = (t & 7) * 32;
  const u16* src = A + (row0 + r)*256 + c0;
  u16* dst = As + r*264 + c0;
#pragma unroll
  for(int i=0;i<4;i++) *(short8*)(dst + i*8) = *(const short8*)(src + i*8);
}

// B in fragment-major order: frag(tile,ks) at ((tile*8+ks)*64 + lane)*8 — 1KB coalesced/wave
__device__ __forceinline__ void mmK256(const u16* As, const u16* __restrict__ WT, int wv,
                                       int colL, int quad, int lane, f32x4 acc[2][4]){
#pragma unroll
  for(int ks=0; ks<8; ks++){
    short8 a0 = *(short8*)(As + colL*264 + ks*32 + quad*8);
    short8 a1 = *(short8*)(As + (colL+16)*264 + ks*32 + quad*8);
#pragma unroll
    for(int ct=0; ct<4; ct++){
      short8 b = *(const short8*)(WT + (((wv*4+ct)*8 + ks)*64 + lane)*8);
      acc[0][ct] = MFMA(a0, b, acc[0][ct]);
      acc[1][ct] = MFMA(a1, b, acc[1][ct]);
    }
  }
}

// ---------------- K6: enc layer 2 dual GEMM + select + mask + remb -> x0 bf16 ----------------
__global__ __launch_bounds__(256,2) void k_enc2(const float* __restrict__ WF, const u16* __restrict__ hb,
                                                const int* __restrict__ roles, const int* __restrict__ maskI,
                                                const u16* __restrict__ WT2F, const u16* __restrict__ WT2U,
                                                u16* __restrict__ x0b){
  __shared__ u16 As[32*264];
  __shared__ int roleS[32], maskS[32];
  long row0 = (long)blockIdx.x*32;
  int t = threadIdx.x;
  stageA256(hb, row0, As);
  if(t<32){ roleS[t]=roles[row0+t]; maskS[t]=maskI[row0+t]; }
  __syncthreads();
  int lane = t & 63, wv = t >> 6;
  int colL = lane & 15, quad = lane >> 4;
  f32x4 accF[2][4] = {};
  f32x4 accU[2][4] = {};
  mmK256(As, WT2F, wv, colL, quad, lane, accF);
  mmK256(As, WT2U, wv, colL, quad, lane, accU);
#pragma unroll
  for(int ct=0; ct<4; ct++){
    int col = wv*64 + ct*16 + colL;
    float bfc = WF[O_bf2+col], buc = WF[O_bu2+col];
    float r0c = WF[O_remb+col], r1c = WF[O_remb+256+col];
#pragma unroll
    for(int rt=0; rt<2; rt++)
#pragma unroll
    for(int reg=0; reg<4; reg++){
      int row = rt*16 + quad*4 + reg;
      float vf = accF[rt][ct][reg] + bfc;
      float vu = accU[rt][ct][reg] + buc;
      int ro = roleS[row];
      float v = ro ? vu : vf;
      v = maskS[row] ? v : 0.f;
      v += ro ? r1c : r0c;
      x0b[(size_t)(row0+row)*256 + col] = f2b(v);
    }
  }
}

// ---------------- K7: qkv GEMM (grid.y selects q/k/v) — verified R12 ----------------
static __device__ const int qkv_b[3] = {O_bq, O_bk, O_bv};
__global__ __launch_bounds__(256,2) void k_qkv(const float* __restrict__ WF, const u16* __restrict__ x0b,
                                               const u16* __restrict__ WTQ, u16* __restrict__ qout){
  __shared__ u16 As[32*264];
  long row0 = (long)blockIdx.x*32;
  int y = blockIdx.y;
  stageA256(x0b, row0, As);
  __syncthreads();
  int t = threadIdx.x;
  int lane = t & 63, wv = t >> 6;
  int colL = lane & 15, quad = lane >> 4;
  f32x4 acc[2][4] = {};
  mmK256(As, WTQ + y*65536, wv, colL, quad, lane, acc);
  u16* outp = qout + (size_t)y*4194304;
  int bo = qkv_b[y];
#pragma unroll
  for(int ct=0; ct<4; ct++){
    int col = wv*64 + ct*16 + colL;
    float bc = WF[bo+col];
#pragma unroll
    for(int rt=0; rt<2; rt++)
#pragma unroll
    for(int reg=0; reg<4; reg++){
      int row = rt*16 + quad*4 + reg;
      outp[(size_t)(row0+row)*256 + col] = f2b(acc[rt][ct][reg] + bc);
    }
  }
}

// ---------------- K8: attention, spill-free split (verified R12) ----------------
__global__ __launch_bounds__(256,1) void k_attn5(const u32* __restrict__ qb, const u32* __restrict__ kb,
                                                 const u32* __restrict__ vb, const int* __restrict__ maskI,
                                                 u32* __restrict__ ctxb){
  __shared__ uint4 Ks4[64*8], Vs4[64*8];
  __shared__ float Ps[64*68];
  __shared__ int maskS[64];
  const int t = threadIdx.x;
  const int b = blockIdx.x, h = blockIdx.y;
  {
    int r = t>>2, c2 = (t&3)*2;
    size_t g = (size_t)(b*64+r)*128 + h*32;
    const uint4* kr = (const uint4*)(kb + g);
    const uint4* vr = (const uint4*)(vb + g);
    int rot = r + (r>>4);
#pragma unroll
    for(int i=0;i<2;i++){
      int c = c2 + i;
      int pc = (c + rot) & 7;
      Ks4[r*8 + pc] = kr[c];
      Vs4[r*8 + pc] = vr[c];
    }
    if(t<64) maskS[t] = maskI[b*64+t];
  }
  const int lane = t & 63;
  const int wv = __builtin_amdgcn_readfirstlane(t>>6);
  const int qq = lane>>2, part = lane&3;
  const int q = wv*16 + qq;
  uint4 qp[8];                                  // packed Q: 32 VGPRs
  {
    const uint4* qr = (const uint4*)(qb + (size_t)(b*64+q)*128 + h*32);
#pragma unroll
    for(int c=0;c<8;c++) qp[c] = qr[c];
  }
  __syncthreads();
  float s[16];
#pragma unroll 1
  for(int jj=0;jj<16;jj++){
    int j = part*16 + jj;
    int rot = j + (j>>4);
    const uint4* kr = Ks4 + j*8;
    float d0=0.f, d1=0.f;
#pragma unroll
    for(int c=0;c<8;c++){
      uint4 w = kr[(c + rot) & 7];
      uint4 qw = qp[c];
      d0 = fmaf(lo16(qw.x), lo16(w.x), d0);
      d1 = fmaf(hi16(qw.x), hi16(w.x), d1);
      d0 = fmaf(lo16(qw.y), lo16(w.y), d0);
      d1 = fmaf(hi16(qw.y), hi16(w.y), d1);
      d0 = fmaf(lo16(qw.z), lo16(w.z), d0);
      d1 = fmaf(hi16(qw.z), hi16(w.z), d1);
      d0 = fmaf(lo16(qw.w), lo16(w.w), d0);
      d1 = fmaf(hi16(qw.w), hi16(w.w), d1);
    }
    s[jj] = maskS[j] ? (d0+d1)*0.125f : -1e9f;
  }
  float mx = s[0];
#pragma unroll
  for(int jj=1;jj<16;jj++) mx = fmaxf(mx, s[jj]);
  mx = fmaxf(mx, __shfl_xor(mx,1,64));
  mx = fmaxf(mx, __shfl_xor(mx,2,64));
  float sum = 0.f;
#pragma unroll
  for(int jj=0;jj<16;jj++){ s[jj] = __expf(s[jj]-mx); sum += s[jj]; }
  sum += __shfl_xor(sum,1,64);
  sum += __shfl_xor(sum,2,64);
  float inv = 1.f/sum;
#pragma unroll
  for(int jj=0;jj<16;jj++) Ps[q*68 + part*16 + jj] = s[jj]*inv;
  __syncthreads();
  float cx[16];
#pragma unroll
  for(int c=0;c<16;c++) cx[c]=0.f;
#pragma unroll 2
  for(int j=0;j<64;j++){
    float p = Ps[q*68 + j];
    int rot = j + (j>>4);
    const uint4* vr = Vs4 + j*8;
    uint4 w0 = vr[(part*2 + rot) & 7];
    uint4 w1 = vr[(part*2 + 1 + rot) & 7];
    cx[0] = fmaf(p, lo16(w0.x), cx[0]);  cx[1] = fmaf(p, hi16(w0.x), cx[1]);
    cx[2] = fmaf(p, lo16(w0.y), cx[2]);  cx[3] = fmaf(p, hi16(w0.y), cx[3]);
    cx[4] = fmaf(p, lo16(w0.z), cx[4]);  cx[5] = fmaf(p, hi16(w0.z), cx[5]);
    cx[6] = fmaf(p, lo16(w0.w), cx[6]);  cx[7] = fmaf(p, hi16(w0.w), cx[7]);
    cx[8] = fmaf(p, lo16(w1.x), cx[8]);  cx[9] = fmaf(p, hi16(w1.x), cx[9]);
    cx[10]= fmaf(p, lo16(w1.y), cx[10]); cx[11]= fmaf(p, hi16(w1.y), cx[11]);
    cx[12]= fmaf(p, lo16(w1.z), cx[12]); cx[13]= fmaf(p, hi16(w1.z), cx[13]);
    cx[14]= fmaf(p, lo16(w1.w), cx[14]); cx[15]= fmaf(p, hi16(w1.w), cx[15]);
  }
  u32 ow[8];
#pragma unroll
  for(int i=0;i<8;i++) ow[i] = pack2(cx[2*i], cx[2*i+1]);
  u32* orow = ctxb + (size_t)(b*64+q)*128 + h*32 + part*8;
  *(uint4*)(orow)     = make_uint4(ow[0],ow[1],ow[2],ow[3]);
  *(uint4*)(orow + 4) = make_uint4(ow[4],ow[5],ow[6],ow[7]);
}

// ---------------- K9: oproj GEMM + residual + LN -> x1 f32 ----------------
__global__ __launch_bounds__(256,2) void k_oproj(const float* __restrict__ WF, const u16* __restrict__ ctxb,
                                                 const u16* __restrict__ x0b, const u16* __restrict__ WTO,
                                                 float* __restrict__ x1){
  __shared__ u16 As[32*264];
  __shared__ float Sred[4][32], Qred[4][32], Mrow[32], Rrow[32];
  long row0 = (long)blockIdx.x*32;
  stageA256(ctxb, row0, As);
  __syncthreads();
  int t = threadIdx.x;
  int lane = t & 63, wv = t >> 6;
  int colL = lane & 15, quad = lane >> 4;
  f32x4 acc[2][4] = {};
  mmK256(As, WTO, wv, colL, quad, lane, acc);
  float S[2][4] = {}, Q[2][4] = {};
#pragma unroll
  for(int ct=0; ct<4; ct++){
    int col = wv*64 + ct*16 + colL;
    float bc = WF[O_bo+col];
#pragma unroll
    for(int rt=0; rt<2; rt++)
#pragma unroll
    for(int reg=0; reg<4; reg++){
      int row = rt*16 + quad*4 + reg;
      float y = acc[rt][ct][reg] + bc + bf2f(x0b[(size_t)(row0+row)*256 + col]);
      acc[rt][ct][reg] = y;
      S[rt][reg] += y; Q[rt][reg] += y*y;
    }
  }
#pragma unroll
  for(int o=1;o<16;o<<=1)
#pragma unroll
  for(int rt=0;rt<2;rt++)
#pragma unroll
  for(int reg=0;reg<4;reg++){ S[rt][reg] += __shfl_xor(S[rt][reg],o); Q[rt][reg] += __shfl_xor(Q[rt][reg],o); }
  if(colL==0){
#pragma unroll
    for(int rt=0;rt<2;rt++)
#pragma unroll
    for(int reg=0;reg<4;reg++){
      Sred[wv][rt*16+quad*4+reg] = S[rt][reg];
      Qred[wv][rt*16+quad*4+reg] = Q[rt][reg];
    }
  }
  __syncthreads();
  if(t<32){
    float s = Sred[0][t]+Sred[1][t]+Sred[2][t]+Sred[3][t];
    float q = Qred[0][t]+Qred[1][t]+Qred[2][t]+Qred[3][t];
    float mean = s*(1.f/256.f);
    float var  = q*(1.f/256.f) - mean*mean;
    Mrow[t] = mean; Rrow[t] = rsqrtf(var + 1e-5f);
  }
  __syncthreads();
#pragma unroll
  for(int ct=0; ct<4; ct++){
    int col = wv*64 + ct*16 + colL;
    float gc = WF[O_ag+col], bc = WF[O_ab+col];
#pragma unroll
    for(int rt=0; rt<2; rt++)
#pragma unroll
    for(int reg=0; reg<4; reg++){
      int row = rt*16 + quad*4 + reg;
      x1[(size_t)(row0+row)*256 + col] = (acc[rt][ct][reg]-Mrow[row])*Rrow[row]*gc + bc;
    }
  }
}

// ---------------- K10: per-pair LN stats over 1280 rel features (verified R12) ----------------
__global__ __launch_bounds__(256) void k_stats(const float* __restrict__ x1, const int* __restrict__ pairs,
                                               float* __restrict__ rsG, float* __restrict__ mrsG){
  int t = threadIdx.x;
  int r = t>>3, t8 = t&7;
  long pr = (long)blockIdx.x*32 + r;
  int b = (int)(pr>>7);
  int i0 = pairs[pr*2], i1 = pairs[pr*2+1];
  const float* ef = x1 + (size_t)(b*64+i0)*256 + t8*32;
  const float* eu = x1 + (size_t)(b*64+i1)*256 + t8*32;
  float S=0.f, Q=0.f;
#pragma unroll
  for(int c=0;c<32;c+=4){
    float4 e4 = *(const float4*)(ef+c);
    float4 u4 = *(const float4*)(eu+c);
    float e[4]={e4.x,e4.y,e4.z,e4.w}, u[4]={u4.x,u4.y,u4.z,u4.w};
#pragma unroll
    for(int j=0;j<4;j++){
      float d = e[j]-u[j], p = e[j]*u[j];
      S += 2.f*e[j] + fabsf(d) + p;
      Q += e[j]*e[j] + u[j]*u[j] + 2.f*d*d + p*p;
    }
  }
#pragma unroll
  for(int o=1;o<8;o<<=1){ S += __shfl_xor(S,o); Q += __shfl_xor(Q,o); }
  if(t8==0){
    float mean = S*(1.f/1280.f);
    float var  = Q*(1.f/1280.f) - mean*mean;
    float rs = rsqrtf(var + 1e-5f);
    rsG[pr] = rs; mrsG[pr] = mean*rs;
  }
}

// ---------------- K11: classifier GEMM, 2-pass K-split + single-stage B prefetch ----------------
// R12 structure; adds a 4-frag B prefetch (+16 VGPR, must stay <=128 for 4 waves/SIMD).
// unroll 1 pins VGPR; the manual prefetch restores cross-iteration load/MFMA overlap
// that unroll 1 otherwise forbids (loads are 1KB coalesced since R10).
__global__ __launch_bounds__(256) void k_cls(const float* __restrict__ WF, const float* __restrict__ x1,
                                             const int* __restrict__ pairs, const u16* __restrict__ WTC,
                                             const float* __restrict__ UG, const float* __restrict__ rsG,
                                             const float* __restrict__ mrsG, float* __restrict__ out){
  __shared__ u16 As[32*512];                   // 32 KB; XOR-swizzled chunks of 8
  int t = threadIdx.x;
  int lane = t & 63, wv = t >> 6;
  int colL = lane & 15, quad = lane >> 4;
  int rxl = colL & 7;
  int r = t>>3, t8 = t&7, rx = r&7;
  long pr = (long)blockIdx.x*32 + r;
  int bb = (int)(pr>>7);
  int i0 = pairs[pr*2], i1 = pairs[pr*2+1];
  const float* ef = x1 + (size_t)(bb*64+i0)*256 + t8*32;
  const float* eu = x1 + (size_t)(bb*64+i1)*256 + t8*32;
  f32x4 acc[2][4] = {};
  // prefetch kst=0 B fragments
  short8 bn[4];
#pragma unroll
  for(int ct=0;ct<4;ct++)
    bn[ct] = *(const short8*)(WTC + (size_t)(((wv*4+ct)*32 + 0)*64 + lane)*8);
#pragma unroll 1
  for(int pass=0; pass<2; pass++){
#pragma unroll
    for(int c=0;c<4;c++){
      float e[8], u[8];
      *(float4*)(e)   = *(const float4*)(ef + c*8);
      *(float4*)(e+4) = *(const float4*)(ef + c*8 + 4);
      *(float4*)(u)   = *(const float4*)(eu + c*8);
      *(float4*)(u+4) = *(const float4*)(eu + c*8 + 4);
      short8 f0, f1;
#pragma unroll
      for(int j=0;j<8;j++){
        float d = e[j]-u[j];
        if(pass==0){ f0[j] = (short)f2b(e[j]);        f1[j] = (short)f2b(u[j]); }
        else       { f0[j] = (short)f2b(fabsf(d));    f1[j] = (short)f2b(e[j]*u[j]); }
      }
      int cc = t8*4 + c;
      *(short8*)(As + r*512 + (( 0 + cc)^rx)*8) = f0;
      *(short8*)(As + r*512 + ((32 + cc)^rx)*8) = f1;
    }
    __syncthreads();
#pragma unroll 1
    for(int ks=0; ks<16; ks++){
      int kst = pass*16 + ks;
      short8 b0[4];
#pragma unroll
      for(int ct=0;ct<4;ct++) b0[ct] = bn[ct];
      if(kst < 31){
#pragma unroll
        for(int ct=0;ct<4;ct++)
          bn[ct] = *(const short8*)(WTC + (size_t)(((wv*4+ct)*32 + kst+1)*64 + lane)*8);
      }
      short8 a0 = *(short8*)(As + colL*512      + ((ks*4+quad)^rxl)*8);
      short8 a1 = *(short8*)(As + (colL+16)*512 + ((ks*4+quad)^rxl)*8);
#pragma unroll
      for(int ct=0;ct<4;ct++){
        acc[0][ct] = MFMA(a0, b0[ct], acc[0][ct]);
        acc[1][ct] = MFMA(a1, b0[ct], acc[1][ct]);
      }
    }
    __syncthreads();
  }
  float rsv[2][4], mrsv[2][4];
#pragma unroll
  for(int rt=0;rt<2;rt++)
#pragma unroll
  for(int reg=0;reg<4;reg++){
    long grow = (long)blockIdx.x*32 + rt*16 + quad*4 + reg;
    rsv[rt][reg] = rsG[grow]; mrsv[rt][reg] = mrsG[grow];
  }
  float plog[2][4] = {};
#pragma unroll
  for(int ct=0; ct<4; ct++){
    int col = wv*64 + ct*16 + colL;
    float Uc = UG[col], Gc = UG[256+col], w2 = WF[O_Wc2+col];
#pragma unroll
    for(int rt=0;rt<2;rt++)
#pragma unroll
    for(int reg=0;reg<4;reg++){
      float h = rsv[rt][reg]*acc[rt][ct][reg] - mrsv[rt][reg]*Gc + Uc;
      h = fmaxf(h, 0.f);
      plog[rt][reg] = fmaf(h, w2, plog[rt][reg]);
    }
  }
#pragma unroll
  for(int o=1;o<16;o<<=1)
#pragma unroll
  for(int rt=0;rt<2;rt++)
#pragma unroll
  for(int reg=0;reg<4;reg++) plog[rt][reg] += __shfl_xor(plog[rt][reg], o);
  float* red = (float*)As;
  if(colL==0){
#pragma unroll
    for(int rt=0;rt<2;rt++)
#pragma unroll
    for(int reg=0;reg<4;reg++) red[wv*32 + rt*16 + quad*4 + reg] = plog[rt][reg];
  }
  __syncthreads();
  if(t<32){
    float l = red[t] + red[32+t] + red[64+t] + red[96+t] + WF[O_bc2];
    out[(long)blockIdx.x*32 + t] = l;
  }
}

// ---------------- workspace layout (bytes) ----------------
#define WS_MASK   3145728u
#define WS_POOLED 3211264u
#define WS_UG     3473408u
#define WS_RS     3475456u
#define WS_MRS    3606528u
#define WS_WT     4194304u
#define WS_WTC    4980736u
#define WS_H      6291456u
#define WS_X0     14680064u
#define WS_Q      23068672u
#define WS_CTX    48234496u
#define WS_X1     56623104u
// total 73,400,320 B (~70 MiB)

extern "C" void kernel_launch(void* const* d_in, const int* in_sizes, int n_in,
                              void* d_out, int out_size, void* d_ws, size_t ws_size,
                              hipStream_t stream){
  char* ws = (char*)d_ws;
  float* WF     = (float*)ws;
  int*   maskI  = (int*)  (ws + WS_MASK);
  float* pooled = (float*)(ws + WS_POOLED);
  float* UG     = (float*)(ws + WS_UG);
  float* rsG    = (float*)(ws + WS_RS);
  float* mrsG   = (float*)(ws + WS_MRS);
  u16*   WT     = (u16*)  (ws + WS_WT);      // 6 x [256][256] bf16 (fragment-major)
  u16*   WTC    = (u16*)  (ws + WS_WTC);     // [256][1024] bf16 (fragment-major)
  u16*   hb     = (u16*)  (ws + WS_H);
  u16*   x0b    = (u16*)  (ws + WS_X0);
  u16*   qkvb   = (u16*)  (ws + WS_Q);       // 3 x [16384][256] bf16
  u16*   ctxb   = (u16*)  (ws + WS_CTX);
  float* x1     = (float*)(ws + WS_X1);

  WPar wp;
  for(int i=0;i<25;i++) wp.src[i] = d_in[4+i];
  wp.traj = (const u32*)d_in[0];
  wp.dst  = WF;

  const void* traj  = d_in[0];
  const int* roles  = (const int*)d_in[1];
  const int* pairs  = (const int*)d_in[2];
  const u32* mraw   = (const u32*)d_in[3];
  float* out = (float*)d_out;

  hipLaunchKernelGGL(k_conv,  dim3((TOTW+255)/256), dim3(256), 0, stream, wp);
  hipLaunchKernelGGL(k_pool,  dim3(256),  dim3(256), 0, stream, traj, mraw, pooled, maskI);
  hipLaunchKernelGGL(k_trans, dim3(96),   dim3(256), 0, stream, WF, WT);
  hipLaunchKernelGGL(k_transc,dim3(64),   dim3(256), 0, stream, WF, WTC);
  hipLaunchKernelGGL(k_prep,  dim3(256),  dim3(256), 0, stream, WF, UG);
  hipLaunchKernelGGL(k_h,     dim3(4096), dim3(256), 0, stream, WF, pooled, roles, (u32*)hb);
  hipLaunchKernelGGL(k_enc2,  dim3(512),  dim3(256), 0, stream, WF, hb, roles, maskI,
                     WT + 0*65536, WT + 1*65536, x0b);
  hipLaunchKernelGGL(k_qkv,   dim3(512,3),dim3(256), 0, stream, WF, x0b, WT + 2*65536, qkvb);
  hipLaunchKernelGGL(k_attn5, dim3(256,4),dim3(256), 0, stream,
                     (const u32*)qkvb, (const u32*)(qkvb+4194304), (const u32*)(qkvb+2*4194304),
                     maskI, (u32*)ctxb);
  hipLaunchKernelGGL(k_oproj, dim3(512),  dim3(256), 0, stream, WF, ctxb, x0b, WT + 5*65536, x1);
  hipLaunchKernelGGL(k_stats, dim3(1024), dim3(256), 0, stream, x1, pairs, rsG, mrsG);
  hipLaunchKernelGGL(k_cls,   dim3(1024), dim3(256), 0, stream, WF, x1, pairs, WTC, UG, rsG, mrsG, out);
}